// Round 8
// baseline (43.669 us; speedup 1.0000x reference)
//
#include <hip/hip_runtime.h>
#include <cstdint>

#define T_STEPS 2048
#define NFEAT   2048
#define A_POS 0.05f
#define A_NEG 0.05f
#define LR    0.01f
#define DECAY 0.60653065971263342f   // exp(-1/2), tau_pos == tau_neg == 2
#define QSCALE 1000.0f               // |kin| <= 0.12707 -> |q| <= 127 (fits i8)
#define OUTSCALE 1.0e-5f             // LR / QSCALE

typedef unsigned char u8;
typedef int i32x4 __attribute__((ext_vector_type(4)));

#define AS1 __attribute__((address_space(1)))
#define AS3 __attribute__((address_space(3)))

__device__ __forceinline__ uint32_t s8(float a, float b, float c, float d) {
  return (uint32_t)(__float2int_rn(a) | (__float2int_rn(b) << 8) |
                    (__float2int_rn(c) << 16) | (__float2int_rn(d) << 24));
}

// ---------------------------------------------------------------------------
// Prep (block-range dispatch):
//  blocks [0,256):     STDP scans -> kinT[j][t] i8 (fixed-point, x1000)
//  blocks [256,1280):  transpose  -> outT[i][t] i8 (binary, exact)
// ---------------------------------------------------------------------------
#define TC   64
#define HALO 32   // decay^32 = 1.1e-7 -> truncation ~1.4e-8 << i8 quantum
__global__ __launch_bounds__(256) void prep_kernel(
    const float* __restrict__ in, const float* __restrict__ outspk,
    u8* __restrict__ kinT, u8* __restrict__ outT) {
  const int bx = blockIdx.x;
  const int tid = threadIdx.x;

  if (bx < 256) {
    // ---- scan role: thread owns feature column j, t-chunk chn ----
    const int jb  = (bx & 7) * 256;
    const int j   = jb + tid;
    const int chn = bx >> 3;              // 0..31
    const int t0  = chn * TC;
    const float d = DECAY;
    const float* cp = in + j;

    // backward halo carry (uniform branch; edge chunk skips)
    float bh = 0.f;
    if (chn < 31) {
#pragma unroll
      for (int u = HALO - 1; u >= 0; --u)
        bh = cp[(size_t)(t0 + TC + u) * NFEAT] + d * bh;
    }
    // main backward scan: kv[u] = B[t0+u] (includes row t0+u)
    float kv[TC];
    {
      float b = bh;
#pragma unroll
      for (int u = TC - 1; u >= 0; --u) {
        b = cp[(size_t)(t0 + u) * NFEAT] + d * b;
        kv[u] = b;
      }
    }
    // forward halo carry
    float f = 0.f;
    if (chn > 0) {
#pragma unroll
      for (int u = 0; u < HALO; ++u)
        f = d * (f + cp[(size_t)(t0 - HALO + u) * NFEAT]);
    }
    // forward pass: combine, quantize, reconstruct iv to advance f
    uint32_t qw[TC / 4];
#pragma unroll
    for (int u = 0; u < TC; ++u) {
      float K  = A_POS * f - A_NEG * kv[u];
      float nb = (u < TC - 1) ? kv[u + 1] : bh;
      float iv = kv[u] - d * nb;            // exact-ish recovery of in[t0+u]
      f = d * (f + iv);
      int q = __float2int_rn(K * QSCALE) & 255;
      uint32_t qs = (uint32_t)q << ((u & 3) * 8);
      qw[u >> 2] = (u & 3) ? (qw[u >> 2] | qs) : qs;
    }
    // thread owns a full 64B line of kinT: 4 x 16B contiguous stores
    uint4* dst = (uint4*)&kinT[(size_t)j * T_STEPS + t0];
#pragma unroll
    for (int g = 0; g < 4; ++g)
      dst[g] = make_uint4(qw[4 * g], qw[4 * g + 1], qw[4 * g + 2], qw[4 * g + 3]);
  } else {
    // ---- transpose role: out_spk [t][i] fp32 -> outT [i][t] i8 ----
    __shared__ float tile[64][65];
    const int bb = bx - 256;
    const int t0 = (bb & 31) * 64;
    const int i0 = (bb >> 5) * 64;
#pragma unroll
    for (int p = 0; p < 4; ++p) {            // float4-vectorized tile load
      int idx = p * 256 + tid;               // 0..1023
      int r = idx >> 4, c4 = idx & 15;
      float4 v = *(const float4*)&outspk[(size_t)(t0 + r) * NFEAT + i0 + c4 * 4];
      tile[r][c4 * 4 + 0] = v.x;
      tile[r][c4 * 4 + 1] = v.y;
      tile[r][c4 * 4 + 2] = v.z;
      tile[r][c4 * 4 + 3] = v.w;
    }
    __syncthreads();
    const int il = tid >> 2, tc = tid & 3;   // thread: 16 t for one i
    uint4 w;
    w.x = s8(tile[tc*16+ 0][il], tile[tc*16+ 1][il], tile[tc*16+ 2][il], tile[tc*16+ 3][il]);
    w.y = s8(tile[tc*16+ 4][il], tile[tc*16+ 5][il], tile[tc*16+ 6][il], tile[tc*16+ 7][il]);
    w.z = s8(tile[tc*16+ 8][il], tile[tc*16+ 9][il], tile[tc*16+10][il], tile[tc*16+11][il]);
    w.w = s8(tile[tc*16+12][il], tile[tc*16+13][il], tile[tc*16+14][il], tile[tc*16+15][il]);
    *(uint4*)&outT[(size_t)(i0 + il) * T_STEPS + t0 + tc * 16] = w;
  }
}

// ---------------------------------------------------------------------------
// i8 GEMM: C[i][j] = W[i][j] + 1e-5 * sum_k A[i][k]*B[j][k]   (i32 exact acc)
// A = outT i8 (binary), B = kinT i8 (kin x1000). Tile 128x128, BK=128,
// 256 threads (4 waves 2x2, wave-tile 64x64) -> A/B LDS-read amp = 2x each.
// 2-buffer LDS (64 KB) -> 2 blocks/CU; barrier drains hidden by sibling block.
// mfma_i32_16x16x64_i8; XOR swizzle per rule 21. Grid 256.
// ---------------------------------------------------------------------------
__global__ __launch_bounds__(256) void stdp_gemm_kernel(
    const u8* __restrict__ A, const u8* __restrict__ B,
    const float* __restrict__ W, float* __restrict__ C) {
  __shared__ u8 ldsA[2][128 * 128];   // 32 KB
  __shared__ u8 ldsB[2][128 * 128];   // 32 KB
  const int tid = threadIdx.x;
  const int lane = tid & 63, wave = tid >> 6;
  const int wm = wave >> 1, wn = wave & 1;     // 2 x 2 wave grid
  const int lr = lane & 15, lk = lane >> 4;

  // XCD-aware decode: 256 blocks -> 16x16 tiles, each XCD a 4x8 chunk
  const int bid = blockIdx.x;
  const int xcd = bid & 7, q = bid >> 3;       // q in [0,32)
  const int it = (xcd >> 1) * 4 + (q >> 3);    // 0..15
  const int jt = (xcd & 1) * 8 + (q & 7);      // 0..15
  const int i0 = it * 128, j0 = jt * 128;

  i32x4 acc[4][4];
#pragma unroll
  for (int m = 0; m < 4; ++m)
#pragma unroll
    for (int n = 0; n < 4; ++n) acc[m][n] = (i32x4){0, 0, 0, 0};

  // per stage: 1024 16B-chunks per matrix, 256 threads -> 4 each
  auto stage = [&](int buf, int kt) {
    const int k0 = kt * 128;
#pragma unroll
    for (int p = 0; p < 4; ++p) {
      int ch = p * 256 + tid;                  // 0..1023
      int r = ch >> 3, c = ch & 7;
      int csw = c ^ (r & 7);                   // inverse-swizzle the SOURCE
      __builtin_amdgcn_global_load_lds(
          (const AS1 void*)(A + (size_t)(i0 + r) * T_STEPS + k0 + csw * 16),
          (AS3 void*)((char*)&ldsA[buf][0] + (p * 256 + wave * 64) * 16),
          16, 0, 0);
    }
#pragma unroll
    for (int p = 0; p < 4; ++p) {
      int ch = p * 256 + tid;
      int r = ch >> 3, c = ch & 7;
      int csw = c ^ (r & 7);
      __builtin_amdgcn_global_load_lds(
          (const AS1 void*)(B + (size_t)(j0 + r) * T_STEPS + k0 + csw * 16),
          (AS3 void*)((char*)&ldsB[buf][0] + (p * 256 + wave * 64) * 16),
          16, 0, 0);
    }
  };

  stage(0, 0);
  asm volatile("s_waitcnt vmcnt(0)" ::: "memory");
  __syncthreads();

  float wv[4][4][4];               // W prefetch target (last K-step)

  int cur = 0;
  const int NKT = T_STEPS / 128;   // 16
  for (int kt = 0; kt < NKT; ++kt) {
    if (kt + 1 < NKT) stage(cur ^ 1, kt + 1);  // prefetch next tile
    else {
      // all staging done: prefetch W through the now-idle vm queue
#pragma unroll
      for (int m = 0; m < 4; ++m)
#pragma unroll
        for (int n = 0; n < 4; ++n) {
          int col = j0 + wn * 64 + n * 16 + lr;
          int row = i0 + wm * 64 + m * 16 + lk * 4;
#pragma unroll
          for (int r = 0; r < 4; ++r)
            wv[m][n][r] = W[(size_t)(row + r) * NFEAT + col];
        }
    }

#pragma unroll
    for (int ks = 0; ks < 2; ++ks) {
      i32x4 af[4], bf[4];
#pragma unroll
      for (int m = 0; m < 4; ++m) {
        int row = wm * 64 + m * 16 + lr;
        int cg = (ks * 4 + lk) ^ (row & 7);    // swizzled read
        af[m] = *(const i32x4*)((const char*)&ldsA[cur][0] + row * 128 + cg * 16);
      }
#pragma unroll
      for (int n = 0; n < 4; ++n) {
        int row = wn * 64 + n * 16 + lr;
        int cg = (ks * 4 + lk) ^ (row & 7);
        bf[n] = *(const i32x4*)((const char*)&ldsB[cur][0] + row * 128 + cg * 16);
      }
      __builtin_amdgcn_s_setprio(1);
#pragma unroll
      for (int m = 0; m < 4; ++m)
#pragma unroll
        for (int n = 0; n < 4; ++n)
          acc[m][n] = __builtin_amdgcn_mfma_i32_16x16x64_i8(af[m], bf[n], acc[m][n], 0, 0, 0);
      __builtin_amdgcn_s_setprio(0);
    }
    __syncthreads();  // prefetch landed + reads done
    cur ^= 1;
  }

  // epilogue: C = W + 1e-5 * acc  (C/D layout: col=lane&15, row=(lane>>4)*4+r)
#pragma unroll
  for (int m = 0; m < 4; ++m)
#pragma unroll
    for (int n = 0; n < 4; ++n) {
      int col = j0 + wn * 64 + n * 16 + lr;
#pragma unroll
      for (int r = 0; r < 4; ++r) {
        int row = i0 + wm * 64 + m * 16 + lk * 4 + r;
        C[(size_t)row * NFEAT + col] = wv[m][n][r] + OUTSCALE * (float)acc[m][n][r];
      }
    }
}

extern "C" void kernel_launch(void* const* d_in, const int* in_sizes, int n_in,
                              void* d_out, int out_size, void* d_ws, size_t ws_size,
                              hipStream_t stream) {
  const float* weight  = (const float*)d_in[0];
  const float* in_spk  = (const float*)d_in[1];
  const float* out_spk = (const float*)d_in[2];
  float* out = (float*)d_out;

  u8* kinT = (u8*)d_ws;                                   // 4 MB i8 [I][T]
  u8* outT = kinT + (size_t)T_STEPS * NFEAT;              // 4 MB i8 [O][T]

  prep_kernel<<<dim3(1280), 256, 0, stream>>>(in_spk, out_spk, kinT, outT);

  stdp_gemm_kernel<<<dim3(256), 256, 0, stream>>>(outT, kinT, weight, out);
}

// Round 9
// 32.900 us; speedup vs baseline: 1.3273x; 1.3273x over previous
//
#include <hip/hip_runtime.h>
#include <cstdint>

#define T_STEPS 2048
#define NFEAT   2048
#define A_POS 0.05f
#define A_NEG 0.05f
#define LR    0.01f
#define DECAY 0.60653065971263342f   // exp(-1/2), tau_pos == tau_neg == 2
#define QSCALE 1000.0f               // |kin| <= 0.12707 -> |q| <= 127 (fits i8)
#define OUTSCALE 1.0e-5f             // LR / QSCALE

typedef unsigned char u8;
typedef int i32x4 __attribute__((ext_vector_type(4)));

#define AS1 __attribute__((address_space(1)))
#define AS3 __attribute__((address_space(3)))

__device__ __forceinline__ uint32_t s8(float a, float b, float c, float d) {
  return (uint32_t)(__float2int_rn(a) | (__float2int_rn(b) << 8) |
                    (__float2int_rn(c) << 16) | (__float2int_rn(d) << 24));
}

// ---------------------------------------------------------------------------
// Prep (block-range dispatch):
//  blocks [0,256):     STDP scans -> kinT[j][t] i8 (fixed-point, x1000)
//  blocks [256,1280):  transpose  -> outT[i][t] i8 (binary, exact)
// Scan keeps the backward-scan array kv[64] in LDS (not registers): avoids
// the 64-deep register array that previously spilled to scratch (VGPR=68).
// Column-per-thread layout kv[u][tid] -> 2-way bank aliasing (free), no sync.
// ---------------------------------------------------------------------------
#define TC   64
#define HALO 32   // decay^32 = 1.1e-7 -> truncation ~1.4e-8 << i8 quantum
__global__ __launch_bounds__(256) void prep_kernel(
    const float* __restrict__ in, const float* __restrict__ outspk,
    u8* __restrict__ kinT, u8* __restrict__ outT) {
  __shared__ union {
    float kv[TC][256];    // scan role: 64 KB
    float tile[64][65];   // transpose role: 16.6 KB
  } sm;
  const int bx = blockIdx.x;
  const int tid = threadIdx.x;

  if (bx < 256) {
    // ---- scan role: thread owns feature column j, t-chunk chn ----
    const int jb  = (bx & 7) * 256;
    const int j   = jb + tid;
    const int chn = bx >> 3;              // 0..31
    const int t0  = chn * TC;
    const float d = DECAY;
    const float* cp = in + j;

    // backward halo carry (uniform branch; edge chunk skips)
    float bh = 0.f;
    if (chn < 31) {
#pragma unroll
      for (int u = HALO - 1; u >= 0; --u)
        bh = cp[(size_t)(t0 + TC + u) * NFEAT] + d * bh;
    }
    // main backward scan -> LDS: kv[u] = B[t0+u] (includes row t0+u)
    {
      float b = bh;
#pragma unroll
      for (int u = TC - 1; u >= 0; --u) {
        b = cp[(size_t)(t0 + u) * NFEAT] + d * b;
        sm.kv[u][tid] = b;
      }
    }
    // forward halo carry
    float f = 0.f;
    if (chn > 0) {
#pragma unroll
      for (int u = 0; u < HALO; ++u)
        f = d * (f + cp[(size_t)(t0 - HALO + u) * NFEAT]);
    }
    // forward pass: combine, quantize; reconstruct in[t] from kv to advance f
    uint32_t qw[TC / 4];
    float cur = sm.kv[0][tid];
#pragma unroll
    for (int u = 0; u < TC; ++u) {
      float nxt = (u < TC - 1) ? sm.kv[u + 1][tid] : bh;
      float K = A_POS * f - A_NEG * cur;
      f = d * (f + (cur - d * nxt));        // in[t0+u] = kv[u] - d*kv[u+1]
      int q = __float2int_rn(K * QSCALE) & 255;
      uint32_t qs = (uint32_t)q << ((u & 3) * 8);
      qw[u >> 2] = (u & 3) ? (qw[u >> 2] | qs) : qs;
      cur = nxt;
    }
    // thread owns a full 64B line of kinT: 4 x 16B contiguous stores
    uint4* dst = (uint4*)&kinT[(size_t)j * T_STEPS + t0];
#pragma unroll
    for (int g = 0; g < 4; ++g)
      dst[g] = make_uint4(qw[4 * g], qw[4 * g + 1], qw[4 * g + 2], qw[4 * g + 3]);
  } else {
    // ---- transpose role: out_spk [t][i] fp32 -> outT [i][t] i8 ----
    const int bb = bx - 256;
    const int t0 = (bb & 31) * 64;
    const int i0 = (bb >> 5) * 64;
#pragma unroll
    for (int p = 0; p < 4; ++p) {            // float4-vectorized tile load
      int idx = p * 256 + tid;               // 0..1023
      int r = idx >> 4, c4 = idx & 15;
      float4 v = *(const float4*)&outspk[(size_t)(t0 + r) * NFEAT + i0 + c4 * 4];
      sm.tile[r][c4 * 4 + 0] = v.x;
      sm.tile[r][c4 * 4 + 1] = v.y;
      sm.tile[r][c4 * 4 + 2] = v.z;
      sm.tile[r][c4 * 4 + 3] = v.w;
    }
    __syncthreads();
    const int il = tid >> 2, tc = tid & 3;   // thread: 16 t for one i
    uint4 w;
    w.x = s8(sm.tile[tc*16+ 0][il], sm.tile[tc*16+ 1][il], sm.tile[tc*16+ 2][il], sm.tile[tc*16+ 3][il]);
    w.y = s8(sm.tile[tc*16+ 4][il], sm.tile[tc*16+ 5][il], sm.tile[tc*16+ 6][il], sm.tile[tc*16+ 7][il]);
    w.z = s8(sm.tile[tc*16+ 8][il], sm.tile[tc*16+ 9][il], sm.tile[tc*16+10][il], sm.tile[tc*16+11][il]);
    w.w = s8(sm.tile[tc*16+12][il], sm.tile[tc*16+13][il], sm.tile[tc*16+14][il], sm.tile[tc*16+15][il]);
    *(uint4*)&outT[(size_t)(i0 + il) * T_STEPS + t0 + tc * 16] = w;
  }
}

// ---------------------------------------------------------------------------
// i8 GEMM (round-7 configuration, measured-good): C = W + 1e-5 * A.Bt
// A = outT i8 (binary), B = kinT i8 (kin x1000). Tile 128x128, BK=128,
// 512 threads (8 waves 2x4, wave-tile 64x32), mfma_i32_16x16x64_i8.
// 3-buffer depth-2 pipeline, counted vmcnt(4); XOR swizzle per rule 21.
// W prefetched at the last K-step (after vmcnt(0), counts untouched).
// ---------------------------------------------------------------------------
__global__ __launch_bounds__(512, 1) void stdp_gemm_kernel(
    const u8* __restrict__ A, const u8* __restrict__ B,
    const float* __restrict__ W, float* __restrict__ C) {
  __shared__ u8 ldsA[3][128 * 128];   // 48 KB
  __shared__ u8 ldsB[3][128 * 128];   // 48 KB
  const int tid = threadIdx.x;
  const int lane = tid & 63, wave = tid >> 6;
  const int wm = wave >> 2, wn = wave & 3;     // 2 x 4 wave grid
  const int lr = lane & 15, lk = lane >> 4;

  // XCD-aware decode: 256 blocks -> 16x16 tiles, each XCD a 4x8 chunk
  const int bid = blockIdx.x;
  const int xcd = bid & 7, q = bid >> 3;       // q in [0,32)
  const int it = (xcd >> 1) * 4 + (q >> 3);    // 0..15
  const int jt = (xcd & 1) * 8 + (q & 7);      // 0..15
  const int i0 = it * 128, j0 = jt * 128;

  i32x4 acc[4][2];
#pragma unroll
  for (int m = 0; m < 4; ++m)
#pragma unroll
    for (int n = 0; n < 2; ++n) acc[m][n] = (i32x4){0, 0, 0, 0};

  // per stage: each thread-slot issues 2 A + 2 B gload_lds (16B = 16 i8)
  auto stage = [&](int buf, int kt) {
    const int k0 = kt * 128;
#pragma unroll
    for (int p = 0; p < 2; ++p) {
      int ch = p * 512 + tid;                  // 0..1023
      int r = ch >> 3, c = ch & 7;
      int csw = c ^ (r & 7);                   // inverse-swizzle the SOURCE
      __builtin_amdgcn_global_load_lds(
          (const AS1 void*)(A + (size_t)(i0 + r) * T_STEPS + k0 + csw * 16),
          (AS3 void*)((char*)&ldsA[buf][0] + (p * 512 + wave * 64) * 16),
          16, 0, 0);
    }
#pragma unroll
    for (int p = 0; p < 2; ++p) {
      int ch = p * 512 + tid;
      int r = ch >> 3, c = ch & 7;
      int csw = c ^ (r & 7);
      __builtin_amdgcn_global_load_lds(
          (const AS1 void*)(B + (size_t)(j0 + r) * T_STEPS + k0 + csw * 16),
          (AS3 void*)((char*)&ldsB[buf][0] + (p * 512 + wave * 64) * 16),
          16, 0, 0);
    }
  };

  stage(0, 0);
  stage(1, 1);                     // 8 loads in flight per wave-slot

  float wv[4][2][4];               // W prefetch target (last K-step)

  const int NKT = T_STEPS / 128;   // 16
  int rb = 0;
  for (int kt = 0; kt < NKT; ++kt) {
    if (kt < NKT - 1) asm volatile("s_waitcnt vmcnt(4)" ::: "memory");
    else              asm volatile("s_waitcnt vmcnt(0)" ::: "memory");
    __builtin_amdgcn_s_barrier();   // tile kt fully in LDS for all waves
    asm volatile("" ::: "memory");

    if (kt + 2 < NKT) {             // overwrites buffer consumed at kt-1
      int sb = rb + 2; if (sb >= 3) sb -= 3;
      stage(sb, kt + 2);
    }

    if (kt == NKT - 1) {            // all counted waits done: W prefetch is
#pragma unroll                      // free to mix into the vm queue now
      for (int m = 0; m < 4; ++m)
#pragma unroll
        for (int n = 0; n < 2; ++n) {
          int col = j0 + wn * 32 + n * 16 + lr;
          int row = i0 + wm * 64 + m * 16 + lk * 4;
#pragma unroll
          for (int r = 0; r < 4; ++r)
            wv[m][n][r] = W[(size_t)(row + r) * NFEAT + col];
        }
    }

#pragma unroll
    for (int ks = 0; ks < 2; ++ks) {
      i32x4 af[4], bf[2];
#pragma unroll
      for (int m = 0; m < 4; ++m) {
        int row = wm * 64 + m * 16 + lr;
        int cg = (ks * 4 + lk) ^ (row & 7);    // swizzled read
        af[m] = *(const i32x4*)((const char*)&ldsA[rb][0] + row * 128 + cg * 16);
      }
#pragma unroll
      for (int n = 0; n < 2; ++n) {
        int row = wn * 32 + n * 16 + lr;
        int cg = (ks * 4 + lk) ^ (row & 7);
        bf[n] = *(const i32x4*)((const char*)&ldsB[rb][0] + row * 128 + cg * 16);
      }
      __builtin_amdgcn_s_setprio(1);
#pragma unroll
      for (int m = 0; m < 4; ++m)
#pragma unroll
        for (int n = 0; n < 2; ++n)
          acc[m][n] = __builtin_amdgcn_mfma_i32_16x16x64_i8(af[m], bf[n], acc[m][n], 0, 0, 0);
      __builtin_amdgcn_s_setprio(0);
    }
    rb = (rb == 2) ? 0 : rb + 1;
  }

  // epilogue: C = W + 1e-5 * acc  (C/D layout: col=lane&15, row=(lane>>4)*4+r)
#pragma unroll
  for (int m = 0; m < 4; ++m)
#pragma unroll
    for (int n = 0; n < 2; ++n) {
      int col = j0 + wn * 32 + n * 16 + lr;
#pragma unroll
      for (int r = 0; r < 4; ++r) {
        int row = i0 + wm * 64 + m * 16 + lk * 4 + r;
        C[(size_t)row * NFEAT + col] = wv[m][n][r] + OUTSCALE * (float)acc[m][n][r];
      }
    }
}

extern "C" void kernel_launch(void* const* d_in, const int* in_sizes, int n_in,
                              void* d_out, int out_size, void* d_ws, size_t ws_size,
                              hipStream_t stream) {
  const float* weight  = (const float*)d_in[0];
  const float* in_spk  = (const float*)d_in[1];
  const float* out_spk = (const float*)d_in[2];
  float* out = (float*)d_out;

  u8* kinT = (u8*)d_ws;                                   // 4 MB i8 [I][T]
  u8* outT = kinT + (size_t)T_STEPS * NFEAT;              // 4 MB i8 [O][T]

  prep_kernel<<<dim3(1280), 256, 0, stream>>>(in_spk, out_spk, kinT, outT);

  stdp_gemm_kernel<<<dim3(256), 512, 0, stream>>>(outT, kinT, weight, out);
}

// Round 10
// 29.749 us; speedup vs baseline: 1.4679x; 1.1059x over previous
//
#include <hip/hip_runtime.h>
#include <cstdint>

#define T_STEPS 2048
#define NFEAT   2048
#define A_POS 0.05f
#define A_NEG 0.05f
#define LR    0.01f
#define DECAY 0.60653065971263342f   // exp(-1/2), tau_pos == tau_neg == 2
#define QSCALE 1000.0f               // |kin| <= 0.12707 -> |q| <= 127 (fits i8)
#define OUTSCALE 1.0e-5f             // LR / QSCALE

typedef unsigned char u8;
typedef int i32x4 __attribute__((ext_vector_type(4)));

#define AS1 __attribute__((address_space(1)))
#define AS3 __attribute__((address_space(3)))

__device__ __forceinline__ uint32_t s8(float a, float b, float c, float d) {
  return (uint32_t)(__float2int_rn(a) | (__float2int_rn(b) << 8) |
                    (__float2int_rn(c) << 16) | (__float2int_rn(d) << 24));
}

// ---------------------------------------------------------------------------
// Prep (round-9 version, measured-good):
//  blocks [0,256):     STDP scans -> kinT[j][t] i8 (fixed-point, x1000)
//  blocks [256,1280):  transpose  -> outT[i][t] i8 (binary, exact)
// Backward-scan array kv lives in LDS (column-per-thread) -> no scratch spill.
// ---------------------------------------------------------------------------
#define TC   64
#define HALO 32   // decay^32 = 1.1e-7 -> truncation ~1.4e-8 << i8 quantum
__global__ __launch_bounds__(256) void prep_kernel(
    const float* __restrict__ in, const float* __restrict__ outspk,
    u8* __restrict__ kinT, u8* __restrict__ outT) {
  __shared__ union {
    float kv[TC][256];    // scan role: 64 KB
    float tile[64][65];   // transpose role: 16.6 KB
  } sm;
  const int bx = blockIdx.x;
  const int tid = threadIdx.x;

  if (bx < 256) {
    // ---- scan role: thread owns feature column j, t-chunk chn ----
    const int jb  = (bx & 7) * 256;
    const int j   = jb + tid;
    const int chn = bx >> 3;              // 0..31
    const int t0  = chn * TC;
    const float d = DECAY;
    const float* cp = in + j;

    // backward halo carry (uniform branch; edge chunk skips)
    float bh = 0.f;
    if (chn < 31) {
#pragma unroll
      for (int u = HALO - 1; u >= 0; --u)
        bh = cp[(size_t)(t0 + TC + u) * NFEAT] + d * bh;
    }
    // main backward scan -> LDS: kv[u] = B[t0+u] (includes row t0+u)
    {
      float b = bh;
#pragma unroll
      for (int u = TC - 1; u >= 0; --u) {
        b = cp[(size_t)(t0 + u) * NFEAT] + d * b;
        sm.kv[u][tid] = b;
      }
    }
    // forward halo carry
    float f = 0.f;
    if (chn > 0) {
#pragma unroll
      for (int u = 0; u < HALO; ++u)
        f = d * (f + cp[(size_t)(t0 - HALO + u) * NFEAT]);
    }
    // forward pass: combine, quantize; reconstruct in[t] from kv to advance f
    uint32_t qw[TC / 4];
    float cur = sm.kv[0][tid];
#pragma unroll
    for (int u = 0; u < TC; ++u) {
      float nxt = (u < TC - 1) ? sm.kv[u + 1][tid] : bh;
      float K = A_POS * f - A_NEG * cur;
      f = d * (f + (cur - d * nxt));        // in[t0+u] = kv[u] - d*kv[u+1]
      int q = __float2int_rn(K * QSCALE) & 255;
      uint32_t qs = (uint32_t)q << ((u & 3) * 8);
      qw[u >> 2] = (u & 3) ? (qw[u >> 2] | qs) : qs;
      cur = nxt;
    }
    // thread owns a full 64B line of kinT: 4 x 16B contiguous stores
    uint4* dst = (uint4*)&kinT[(size_t)j * T_STEPS + t0];
#pragma unroll
    for (int g = 0; g < 4; ++g)
      dst[g] = make_uint4(qw[4 * g], qw[4 * g + 1], qw[4 * g + 2], qw[4 * g + 3]);
  } else {
    // ---- transpose role: out_spk [t][i] fp32 -> outT [i][t] i8 ----
    const int bb = bx - 256;
    const int t0 = (bb & 31) * 64;
    const int i0 = (bb >> 5) * 64;
#pragma unroll
    for (int p = 0; p < 4; ++p) {            // float4-vectorized tile load
      int idx = p * 256 + tid;               // 0..1023
      int r = idx >> 4, c4 = idx & 15;
      float4 v = *(const float4*)&outspk[(size_t)(t0 + r) * NFEAT + i0 + c4 * 4];
      sm.tile[r][c4 * 4 + 0] = v.x;
      sm.tile[r][c4 * 4 + 1] = v.y;
      sm.tile[r][c4 * 4 + 2] = v.z;
      sm.tile[r][c4 * 4 + 3] = v.w;
    }
    __syncthreads();
    const int il = tid >> 2, tc = tid & 3;   // thread: 16 t for one i
    uint4 w;
    w.x = s8(sm.tile[tc*16+ 0][il], sm.tile[tc*16+ 1][il], sm.tile[tc*16+ 2][il], sm.tile[tc*16+ 3][il]);
    w.y = s8(sm.tile[tc*16+ 4][il], sm.tile[tc*16+ 5][il], sm.tile[tc*16+ 6][il], sm.tile[tc*16+ 7][il]);
    w.z = s8(sm.tile[tc*16+ 8][il], sm.tile[tc*16+ 9][il], sm.tile[tc*16+10][il], sm.tile[tc*16+11][il]);
    w.w = s8(sm.tile[tc*16+12][il], sm.tile[tc*16+13][il], sm.tile[tc*16+14][il], sm.tile[tc*16+15][il]);
    *(uint4*)&outT[(size_t)(i0 + il) * T_STEPS + t0 + tc * 16] = w;
  }
}

// ---------------------------------------------------------------------------
// i8 GEMM: C = W + 1e-5 * A.Bt  (i32 exact acc), tile 128x128, BK=128.
// 512 threads. In-block K-split: waves 0-3 take k-slice 0, waves 4-7 k-slice
// 1, of the same 2x2 grid of 64x64 wave-tiles -> LDS reads/K-step drop
// 96->64 KB (ops/LDS-byte 42.7 -> 64) while keeping R7's proven 3-buffer
// counted-vmcnt(4) schedule. i32 partials combined via one-time LDS exchange
// (reusing staging buffers); waves 4-7 add + fused W epilogue.
// ---------------------------------------------------------------------------
__global__ __launch_bounds__(512, 1) void stdp_gemm_kernel(
    const u8* __restrict__ A, const u8* __restrict__ B,
    const float* __restrict__ W, float* __restrict__ C) {
  __shared__ u8 lds[3][32768];        // per buf: A 16 KB @0, B 16 KB @16384
  const int tid = threadIdx.x;
  const int lane = tid & 63, wave = tid >> 6;
  const int ks = wave >> 2;                    // k-slice (0: k<64, 1: k>=64)
  const int wm = (wave >> 1) & 1, wn = wave & 1;  // 2x2 grid of 64x64 tiles
  const int lr = lane & 15, lk = lane >> 4;

  // XCD-aware decode: 256 blocks -> 16x16 tiles, each XCD a 4x8 chunk
  const int bid = blockIdx.x;
  const int xcd = bid & 7, q = bid >> 3;       // q in [0,32)
  const int it = (xcd >> 1) * 4 + (q >> 3);    // 0..15
  const int jt = (xcd & 1) * 8 + (q & 7);      // 0..15
  const int i0 = it * 128, j0 = jt * 128;

  i32x4 acc[4][4];
#pragma unroll
  for (int m = 0; m < 4; ++m)
#pragma unroll
    for (int n = 0; n < 4; ++n) acc[m][n] = (i32x4){0, 0, 0, 0};

  // per stage: each thread-slot issues 2 A + 2 B gload_lds (16B = 16 i8)
  auto stage = [&](int buf, int kt) {
    const int k0 = kt * 128;
#pragma unroll
    for (int p = 0; p < 2; ++p) {
      int ch = p * 512 + tid;                  // 0..1023
      int r = ch >> 3, c = ch & 7;
      int csw = c ^ (r & 7);                   // inverse-swizzle the SOURCE
      __builtin_amdgcn_global_load_lds(
          (const AS1 void*)(A + (size_t)(i0 + r) * T_STEPS + k0 + csw * 16),
          (AS3 void*)((char*)&lds[buf][0] + (p * 512 + wave * 64) * 16),
          16, 0, 0);
    }
#pragma unroll
    for (int p = 0; p < 2; ++p) {
      int ch = p * 512 + tid;
      int r = ch >> 3, c = ch & 7;
      int csw = c ^ (r & 7);
      __builtin_amdgcn_global_load_lds(
          (const AS1 void*)(B + (size_t)(j0 + r) * T_STEPS + k0 + csw * 16),
          (AS3 void*)((char*)&lds[buf][16384] + (p * 512 + wave * 64) * 16),
          16, 0, 0);
    }
  };

  stage(0, 0);
  stage(1, 1);                     // 8 load-instrs in flight per wave

  float wv[4][4][4];               // W prefetch target (waves 4-7, last step)

  const int NKT = T_STEPS / 128;   // 16
  int rb = 0;
  for (int kt = 0; kt < NKT; ++kt) {
    if (kt < NKT - 1) asm volatile("s_waitcnt vmcnt(4)" ::: "memory");
    else              asm volatile("s_waitcnt vmcnt(0)" ::: "memory");
    __builtin_amdgcn_s_barrier();   // tile kt fully in LDS for all waves
    asm volatile("" ::: "memory");

    if (kt + 2 < NKT) {             // overwrites buffer consumed at kt-1
      int sb = rb + 2; if (sb >= 3) sb -= 3;
      stage(sb, kt + 2);
    }

    if (kt == NKT - 1 && wave >= 4) {  // vm queue idle: free W prefetch
#pragma unroll
      for (int m = 0; m < 4; ++m)
#pragma unroll
        for (int n = 0; n < 4; ++n) {
          int col = j0 + wn * 64 + n * 16 + lr;
          int row = i0 + wm * 64 + m * 16 + lk * 4;
#pragma unroll
          for (int r = 0; r < 4; ++r)
            wv[m][n][r] = W[(size_t)(row + r) * NFEAT + col];
        }
    }

    {
      i32x4 af[4], bf[4];
#pragma unroll
      for (int m = 0; m < 4; ++m) {
        int row = wm * 64 + m * 16 + lr;
        int cg = (ks * 4 + lk) ^ (row & 7);    // swizzled read
        af[m] = *(const i32x4*)((const char*)&lds[rb][0] + row * 128 + cg * 16);
      }
#pragma unroll
      for (int n = 0; n < 4; ++n) {
        int row = wn * 64 + n * 16 + lr;
        int cg = (ks * 4 + lk) ^ (row & 7);
        bf[n] = *(const i32x4*)((const char*)&lds[rb][16384] + row * 128 + cg * 16);
      }
      __builtin_amdgcn_s_setprio(1);
#pragma unroll
      for (int m = 0; m < 4; ++m)
#pragma unroll
        for (int n = 0; n < 4; ++n)
          acc[m][n] = __builtin_amdgcn_mfma_i32_16x16x64_i8(af[m], bf[n], acc[m][n], 0, 0, 0);
      __builtin_amdgcn_s_setprio(0);
    }
    rb = (rb == 2) ? 0 : rb + 1;
  }

  // ---- combine k-slices via LDS exchange (staging buffers are retired) ----
  __syncthreads();                    // all MFMA + last LDS reads done
  int* xch = (int*)&lds[0][0];        // 64 KB needed, 96 KB available
  if (wave < 4) {
#pragma unroll
    for (int m = 0; m < 4; ++m)
#pragma unroll
      for (int n = 0; n < 4; ++n)
        *(i32x4*)(xch + wave * 4096 + (m * 4 + n) * 256 + lane * 4) = acc[m][n];
  }
  __syncthreads();
  if (wave >= 4) {
    const int w2 = wave - 4;          // partner with same (wm,wn), ks=0
#pragma unroll
    for (int m = 0; m < 4; ++m)
#pragma unroll
      for (int n = 0; n < 4; ++n) {
        i32x4 part = *(const i32x4*)(xch + w2 * 4096 + (m * 4 + n) * 256 + lane * 4);
        acc[m][n] += part;
        int col = j0 + wn * 64 + n * 16 + lr;
#pragma unroll
        for (int r = 0; r < 4; ++r) {
          int row = i0 + wm * 64 + m * 16 + lk * 4 + r;
          C[(size_t)row * NFEAT + col] = wv[m][n][r] + OUTSCALE * (float)acc[m][n][r];
        }
      }
  }
}

extern "C" void kernel_launch(void* const* d_in, const int* in_sizes, int n_in,
                              void* d_out, int out_size, void* d_ws, size_t ws_size,
                              hipStream_t stream) {
  const float* weight  = (const float*)d_in[0];
  const float* in_spk  = (const float*)d_in[1];
  const float* out_spk = (const float*)d_in[2];
  float* out = (float*)d_out;

  u8* kinT = (u8*)d_ws;                                   // 4 MB i8 [I][T]
  u8* outT = kinT + (size_t)T_STEPS * NFEAT;              // 4 MB i8 [O][T]

  prep_kernel<<<dim3(1280), 256, 0, stream>>>(in_spk, out_spk, kinT, outT);

  stdp_gemm_kernel<<<dim3(256), 512, 0, stream>>>(outT, kinT, weight, out);
}